// Round 1
// baseline (20896.783 us; speedup 1.0000x reference)
//
#include <hip/hip_runtime.h>

// Problem constants (from setup_inputs): x[16,64,64,128] fp32, dicts [128,{64,128,256,512}]
#define NROWS 65536
#define CDIM  128
#define NC    8388608  // NROWS*CDIM

// ---------------- kernel 0: per-column squared norms of all dicts ----------------
__global__ void vq_norms(const float* __restrict__ D0, const float* __restrict__ D1,
                         const float* __restrict__ D2, const float* __restrict__ D3,
                         float* __restrict__ nrm) {
  int g = blockIdx.x * 256 + threadIdx.x;
  if (g >= 960) return;
  const float* D; int K, k;
  if (g < 64)       { D = D0; K = 64;  k = g; }
  else if (g < 192) { D = D1; K = 128; k = g - 64; }
  else if (g < 448) { D = D2; K = 256; k = g - 192; }
  else              { D = D3; K = 512; k = g - 448; }
  float s = 0.f;
  for (int c = 0; c < 128; ++c) { float v = D[c * K + k]; s = fmaf(v, v, s); }
  nrm[g] = s;
}

// ---------------- main kernel helpers ----------------
// Each block: 128 rows, 256 threads (2 threads per row: sub=0 handles cols [kb,kb+16),
// sub=1 handles [kb+16,kb+32) of each staged 32-column tile).
template<int K>
__device__ __forceinline__ void procDict(
    const float* __restrict__ D, const float* __restrict__ nrmseg,
    const float (&xs)[128], float4* sD, int sub4, int subk,
    float& best, int& bkk, float& bss, float& bnn)
{
  best = 1e30f; bkk = 0; bss = 0.f; bnn = 0.f;
  for (int kb = 0; kb < K; kb += 32) {
    __syncthreads();
    // stage D[:, kb..kb+32) -> LDS, 1024 float4, 4 per thread, layout [c][8 float4]
    #pragma unroll
    for (int q = 0; q < 4; ++q) {
      int idx = threadIdx.x + q * 256;
      int c = idx >> 3, c4 = idx & 7;
      sD[idx] = *(const float4*)(D + c * K + kb + c4 * 4);
    }
    __syncthreads();

    float acc[16];
    #pragma unroll
    for (int u = 0; u < 16; ++u) acc[u] = 0.f;
    #pragma unroll
    for (int c = 0; c < 128; ++c) {
      float xc = xs[c];
      float4 a0 = sD[c * 8 + sub4 + 0];
      float4 a1 = sD[c * 8 + sub4 + 1];
      float4 a2 = sD[c * 8 + sub4 + 2];
      float4 a3 = sD[c * 8 + sub4 + 3];
      float dv[16] = {a0.x,a0.y,a0.z,a0.w, a1.x,a1.y,a1.z,a1.w,
                      a2.x,a2.y,a2.z,a2.w, a3.x,a3.y,a3.z,a3.w};
      #pragma unroll
      for (int u = 0; u < 16; ++u) acc[u] = fmaf(xc, dv[u], acc[u]);
    }
    int kbase = kb + subk;
    #pragma unroll
    for (int u = 0; u < 16; ++u) {
      float nv = nrmseg[kbase + u];
      float cr = fmaf(-2.f, acc[u], nv);   // ||d||^2 - 2 x.d
      if (cr < best) { best = cr; bkk = kbase + u; bss = acc[u]; bnn = nv; }
    }
  }
}

__global__ __launch_bounds__(256, 2) void vq_main(
    const float* __restrict__ x,
    const float* __restrict__ D0, const float* __restrict__ D1,
    const float* __restrict__ D2, const float* __restrict__ D3,
    const float* __restrict__ alpha_p, const float* __restrict__ gamma_p,
    const float* __restrict__ nrm, float* __restrict__ out,
    float* __restrict__ partials)
{
  __shared__ float4 sD[1024];       // 16 KB stage buffer (128 c x 32 cols)
  __shared__ float4 mg[128][4];     // merge: crit, k, s, n per (row, dict)
  __shared__ float wr[4];

  const int t = threadIdx.x;
  const int rl = t & 127;
  const int sub = t >> 7;
  const int sub4 = sub * 4, subk = sub * 16;
  const int row = blockIdx.x * 128 + rl;

  // x row fully in registers; also ||x||^2
  float xs[128];
  float xsq = 0.f;
  const float4* xp = (const float4*)(x + (size_t)row * CDIM);
  #pragma unroll
  for (int i = 0; i < 32; ++i) {
    float4 v = xp[i];
    xs[4*i+0] = v.x; xs[4*i+1] = v.y; xs[4*i+2] = v.z; xs[4*i+3] = v.w;
    xsq = fmaf(v.x, v.x, xsq); xsq = fmaf(v.y, v.y, xsq);
    xsq = fmaf(v.z, v.z, xsq); xsq = fmaf(v.w, v.w, xsq);
  }

  float best[4]; int bk[4]; float bs_[4], bn_[4];
  procDict< 64>(D0, nrm +   0, xs, sD, sub4, subk, best[0], bk[0], bs_[0], bn_[0]);
  procDict<128>(D1, nrm +  64, xs, sD, sub4, subk, best[1], bk[1], bs_[1], bn_[1]);
  procDict<256>(D2, nrm + 192, xs, sD, sub4, subk, best[2], bk[2], bs_[2], bn_[2]);
  procDict<512>(D3, nrm + 448, xs, sD, sub4, subk, best[3], bk[3], bs_[3], bn_[3]);

  // merge the two column-halves per row (sub1 publishes; sub0 merges; ties keep sub0 = smaller k)
  if (sub == 1) {
    #pragma unroll
    for (int i = 0; i < 4; ++i)
      mg[rl][i] = make_float4(best[i], __int_as_float(bk[i]), bs_[i], bn_[i]);
  }
  __syncthreads();

  float rowloss = 0.f;
  if (sub == 0) {
    const float a = alpha_p[0];
    float gm[4];
    #pragma unroll
    for (int i = 0; i < 4; ++i) gm[i] = gamma_p[i];
    #pragma unroll
    for (int i = 0; i < 4; ++i) {
      float4 m = mg[rl][i];
      if (m.x < best[i]) { best[i] = m.x; bk[i] = __float_as_int(m.y); bs_[i] = m.z; bn_[i] = m.w; }
      // sum_c (x - a*d)^2 = xsq - 2a*s + a^2*n
      rowloss += gm[i] * (xsq - 2.f * a * bs_[i] + a * a * bn_[i]);
    }
    const float* p0 = D0 + bk[0];
    const float* p1 = D1 + bk[1];
    const float* p2 = D2 + bk[2];
    const float* p3 = D3 + bk[3];
    const float w0 = a * gm[0], w1 = a * gm[1], w2 = a * gm[2], w3 = a * gm[3];
    float4* op = (float4*)(out + (size_t)row * CDIM);
    #pragma unroll 4
    for (int c4 = 0; c4 < 32; ++c4) {
      int cb = c4 * 4;
      float4 o;
      o.x = w0*p0[(cb+0)*64] + w1*p1[(cb+0)*128] + w2*p2[(cb+0)*256] + w3*p3[(cb+0)*512];
      o.y = w0*p0[(cb+1)*64] + w1*p1[(cb+1)*128] + w2*p2[(cb+1)*256] + w3*p3[(cb+1)*512];
      o.z = w0*p0[(cb+2)*64] + w1*p1[(cb+2)*128] + w2*p2[(cb+2)*256] + w3*p3[(cb+2)*512];
      o.w = w0*p0[(cb+3)*64] + w1*p1[(cb+3)*128] + w2*p2[(cb+3)*256] + w3*p3[(cb+3)*512];
      op[c4] = o;
    }
  }

  // deterministic block reduction of rowloss (sub1 contributes 0)
  #pragma unroll
  for (int off = 32; off > 0; off >>= 1)
    rowloss += __shfl_down(rowloss, off);
  if ((t & 63) == 0) wr[t >> 6] = rowloss;
  __syncthreads();
  if (t == 0) partials[blockIdx.x] = wr[0] + wr[1] + wr[2] + wr[3];
}

// ---------------- kernel 2: final deterministic loss reduction ----------------
__global__ void vq_reduce(const float* __restrict__ partials, float* __restrict__ lossp) {
  __shared__ float wr[4];
  int t = threadIdx.x;  // 256 threads, 512 partials
  float v = partials[t] + partials[t + 256];
  #pragma unroll
  for (int off = 32; off > 0; off >>= 1) v += __shfl_down(v, off);
  if ((t & 63) == 0) wr[t >> 6] = v;
  __syncthreads();
  // loss = (1 + 0.25) * sum_i gamma_i * mean((x-q)^2); mean denom = NC
  if (t == 0) lossp[0] = (wr[0] + wr[1] + wr[2] + wr[3]) * (1.25f / 8388608.f);
}

extern "C" void kernel_launch(void* const* d_in, const int* in_sizes, int n_in,
                              void* d_out, int out_size, void* d_ws, size_t ws_size,
                              hipStream_t stream) {
  const float* x  = (const float*)d_in[0];
  const float* D0 = (const float*)d_in[1];
  const float* D1 = (const float*)d_in[2];
  const float* D2 = (const float*)d_in[3];
  const float* D3 = (const float*)d_in[4];
  const float* alpha = (const float*)d_in[5];
  const float* gamma = (const float*)d_in[6];
  float* out = (float*)d_out;

  float* nrm      = (float*)d_ws;        // 960 floats
  float* partials = nrm + 960;           // 512 floats

  vq_norms<<<4, 256, 0, stream>>>(D0, D1, D2, D3, nrm);
  vq_main<<<512, 256, 0, stream>>>(x, D0, D1, D2, D3, alpha, gamma, nrm, out, partials);
  vq_reduce<<<1, 256, 0, stream>>>(partials, out + NC);
}

// Round 2
// 265.295 us; speedup vs baseline: 78.7682x; 78.7682x over previous
//
#include <hip/hip_runtime.h>

// x[65536,128] fp32; dicts D_i[128,K_i], K = {64,128,256,512}; out = [65536*128 floats] + [1 loss]
#define CDIM 128
#define NC   8388608
#define NBLK 1024   // 64 rows per block

// ---------------- kernel 0: per-column squared norms of all dicts ----------------
__global__ void vq_norms(const float* __restrict__ D0, const float* __restrict__ D1,
                         const float* __restrict__ D2, const float* __restrict__ D3,
                         float* __restrict__ nrm) {
  int g = blockIdx.x * 256 + threadIdx.x;
  if (g >= 960) return;
  const float* D; int K, k;
  if (g < 64)       { D = D0; K = 64;  k = g; }
  else if (g < 192) { D = D1; K = 128; k = g - 64; }
  else if (g < 448) { D = D2; K = 256; k = g - 192; }
  else              { D = D3; K = 512; k = g - 448; }
  float s = 0.f;
  for (int c = 0; c < 128; ++c) { float v = D[c * K + k]; s = fmaf(v, v, s); }
  nrm[g] = s;
}

// 16 explicit FMAs into 4 named float4 accumulators (no arrays -> no scratch risk)
#define FMA4(A, DV) \
  A.x = fmaf(xc, DV.x, A.x); A.y = fmaf(xc, DV.y, A.y); \
  A.z = fmaf(xc, DV.z, A.z); A.w = fmaf(xc, DV.w, A.w);

#define UPD(AV, NV, OFF) { float cr = fmaf(-2.f, (AV), (NV)); \
  if (cr < best) { best = cr; bk = colbase + (OFF); bs = (AV); bn = (NV); } }

// Each wave handles 16 columns of every 64-column tile of dict D.
// x is streamed from global (L1/L2-hot) one float4 at a time.
template<int K>
__device__ __forceinline__ void procDict(
    const float* __restrict__ D, const float* __restrict__ nseg,
    const float* __restrict__ xrow, int wcol,
    float& best, int& bk, float& bs, float& bn)
{
  best = 1e30f; bk = 0; bs = 0.f; bn = 0.f;
  for (int tb = 0; tb < K; tb += 64) {
    const int colbase = tb + wcol;                  // wave-uniform
    const float* __restrict__ Dp = D + colbase;
    float4 a0 = make_float4(0.f,0.f,0.f,0.f);
    float4 a1 = a0, a2 = a0, a3 = a0;
    #pragma unroll 2
    for (int c4 = 0; c4 < 32; ++c4) {
      float4 xv = *(const float4*)(xrow + c4 * 4);
      #pragma unroll
      for (int cc = 0; cc < 4; ++cc) {
        float xc = (cc == 0) ? xv.x : (cc == 1) ? xv.y : (cc == 2) ? xv.z : xv.w;
        const float* dr = Dp + (c4 * 4 + cc) * K;   // wave-uniform address
        float4 d0 = *(const float4*)(dr);
        float4 d1 = *(const float4*)(dr + 4);
        float4 d2 = *(const float4*)(dr + 8);
        float4 d3 = *(const float4*)(dr + 12);
        FMA4(a0, d0) FMA4(a1, d1) FMA4(a2, d2) FMA4(a3, d3)
      }
    }
    float4 n0 = *(const float4*)(nseg + colbase);
    float4 n1 = *(const float4*)(nseg + colbase + 4);
    float4 n2 = *(const float4*)(nseg + colbase + 8);
    float4 n3 = *(const float4*)(nseg + colbase + 12);
    UPD(a0.x, n0.x, 0)  UPD(a0.y, n0.y, 1)  UPD(a0.z, n0.z, 2)  UPD(a0.w, n0.w, 3)
    UPD(a1.x, n1.x, 4)  UPD(a1.y, n1.y, 5)  UPD(a1.z, n1.z, 6)  UPD(a1.w, n1.w, 7)
    UPD(a2.x, n2.x, 8)  UPD(a2.y, n2.y, 9)  UPD(a2.z, n2.z, 10) UPD(a2.w, n2.w, 11)
    UPD(a3.x, n3.x, 12) UPD(a3.y, n3.y, 13) UPD(a3.z, n3.z, 14) UPD(a3.w, n3.w, 15)
  }
}

__global__ __launch_bounds__(256, 4) void vq_main(
    const float* __restrict__ x,
    const float* __restrict__ D0, const float* __restrict__ D1,
    const float* __restrict__ D2, const float* __restrict__ D3,
    const float* __restrict__ alpha_p, const float* __restrict__ gamma_p,
    const float* __restrict__ nrm, float* __restrict__ out,
    float* __restrict__ partials)
{
  __shared__ float4 cand[4][4][64];   // [dict][wave][row] : (crit, k, s, n)  16 KB
  __shared__ int    kidx[4][64];
  __shared__ float  wr[4];

  const int t    = threadIdx.x;
  const int lane = t & 63;            // row within block
  const int wid  = t >> 6;            // wave id = column sub-slice / later dict id / c-quarter
  const int row  = blockIdx.x * 64 + lane;
  const float* __restrict__ xrow = x + (size_t)row * CDIM;
  const int wcol = __builtin_amdgcn_readfirstlane(wid * 16);  // wave-uniform col offset

  float best; int bk; float bs, bn;
  procDict< 64>(D0, nrm +   0, xrow, wcol, best, bk, bs, bn);
  cand[0][wid][lane] = make_float4(best, __int_as_float(bk), bs, bn);
  procDict<128>(D1, nrm +  64, xrow, wcol, best, bk, bs, bn);
  cand[1][wid][lane] = make_float4(best, __int_as_float(bk), bs, bn);
  procDict<256>(D2, nrm + 192, xrow, wcol, best, bk, bs, bn);
  cand[2][wid][lane] = make_float4(best, __int_as_float(bk), bs, bn);
  procDict<512>(D3, nrm + 448, xrow, wcol, best, bk, bs, bn);
  cand[3][wid][lane] = make_float4(best, __int_as_float(bk), bs, bn);
  __syncthreads();

  // merge: wave `wid` merges dict `wid` for row `lane`; ties -> lowest column index
  const float a = alpha_p[0];
  float4 m = cand[wid][0][lane];
  float mb = m.x; int mk = __float_as_int(m.y); float ms = m.z, mn = m.w;
  #pragma unroll
  for (int w = 1; w < 4; ++w) {
    float4 c2 = cand[wid][w][lane];
    int k2 = __float_as_int(c2.y);
    if (c2.x < mb || (c2.x == mb && k2 < mk)) { mb = c2.x; mk = k2; ms = c2.z; mn = c2.w; }
  }
  kidx[wid][lane] = mk;
  // loss partial: dict `wid` term for this row; wave 0 adds (sum gamma)*||x||^2
  float g = gamma_p[wid];
  float rl = g * (a * a * mn - 2.f * a * ms);
  if (wid == 0) {
    float gsum = gamma_p[0] + gamma_p[1] + gamma_p[2] + gamma_p[3];
    float xsq = 0.f;
    #pragma unroll 4
    for (int c4 = 0; c4 < 32; ++c4) {
      float4 v = *(const float4*)(xrow + c4 * 4);
      xsq = fmaf(v.x, v.x, xsq); xsq = fmaf(v.y, v.y, xsq);
      xsq = fmaf(v.z, v.z, xsq); xsq = fmaf(v.w, v.w, xsq);
    }
    rl = fmaf(gsum, xsq, rl);
  }

  // deterministic block reduction of rl
  #pragma unroll
  for (int off = 32; off > 0; off >>= 1) rl += __shfl_down(rl, off);
  if ((t & 63) == 0) wr[t >> 6] = rl;
  __syncthreads();              // also publishes kidx for the epilogue
  if (t == 0) partials[blockIdx.x] = wr[0] + wr[1] + wr[2] + wr[3];

  // epilogue: thread (row=lane, c-quarter=wid) writes 32 output channels
  const int k0 = kidx[0][lane], k1 = kidx[1][lane], k2 = kidx[2][lane], k3 = kidx[3][lane];
  const float w0 = a * gamma_p[0], w1 = a * gamma_p[1];
  const float w2 = a * gamma_p[2], w3 = a * gamma_p[3];
  const float* p0 = D0 + k0;
  const float* p1 = D1 + k1;
  const float* p2 = D2 + k2;
  const float* p3 = D3 + k3;
  float4* op = (float4*)(out + (size_t)row * CDIM);
  const int cbase = wid * 32;
  #pragma unroll
  for (int c4 = 0; c4 < 8; ++c4) {
    int cb = cbase + c4 * 4;
    float4 o;
    o.x = w0*p0[(cb+0)*64] + w1*p1[(cb+0)*128] + w2*p2[(cb+0)*256] + w3*p3[(cb+0)*512];
    o.y = w0*p0[(cb+1)*64] + w1*p1[(cb+1)*128] + w2*p2[(cb+1)*256] + w3*p3[(cb+1)*512];
    o.z = w0*p0[(cb+2)*64] + w1*p1[(cb+2)*128] + w2*p2[(cb+2)*256] + w3*p3[(cb+2)*512];
    o.w = w0*p0[(cb+3)*64] + w1*p1[(cb+3)*128] + w2*p2[(cb+3)*256] + w3*p3[(cb+3)*512];
    op[wid * 8 + c4] = o;
  }
}

// ---------------- kernel 2: final deterministic loss reduction ----------------
__global__ void vq_reduce(const float* __restrict__ partials, float* __restrict__ lossp) {
  __shared__ float wr[4];
  int t = threadIdx.x;  // 256 threads, 1024 partials
  float v = partials[t] + partials[t + 256] + partials[t + 512] + partials[t + 768];
  #pragma unroll
  for (int off = 32; off > 0; off >>= 1) v += __shfl_down(v, off);
  if ((t & 63) == 0) wr[t >> 6] = v;
  __syncthreads();
  if (t == 0) lossp[0] = (wr[0] + wr[1] + wr[2] + wr[3]) * (1.25f / 8388608.f);
}

extern "C" void kernel_launch(void* const* d_in, const int* in_sizes, int n_in,
                              void* d_out, int out_size, void* d_ws, size_t ws_size,
                              hipStream_t stream) {
  const float* x  = (const float*)d_in[0];
  const float* D0 = (const float*)d_in[1];
  const float* D1 = (const float*)d_in[2];
  const float* D2 = (const float*)d_in[3];
  const float* D3 = (const float*)d_in[4];
  const float* alpha = (const float*)d_in[5];
  const float* gamma = (const float*)d_in[6];
  float* out = (float*)d_out;

  float* nrm      = (float*)d_ws;        // 960 floats
  float* partials = nrm + 960;           // 1024 floats

  vq_norms<<<4, 256, 0, stream>>>(D0, D1, D2, D3, nrm);
  vq_main<<<NBLK, 256, 0, stream>>>(x, D0, D1, D2, D3, alpha, gamma, nrm, out, partials);
  vq_reduce<<<1, 256, 0, stream>>>(partials, out + NC);
}